// Round 3
// baseline (204.230 us; speedup 1.0000x reference)
//
#include <hip/hip_runtime.h>
#include <hip/hip_bf16.h>
#include <math.h>

#define N 2048
#define NC 8

// ws layout:
//   [0, 64)             : double acc[8]        (zeroed by k_prep block 0)
//   [64, 64+64K)        : float  A[8][2048]
//   [64+64K, 64+128K)   : int    lohi[8][2048] (lo | hi<<16, per ORIGINAL row)
//   [64+128K, +4)       : unsigned counter     (ticket for fused finalize)

// ---------------- Kernel 1: fused A-sum + counting-rank GT + acc zeroing ------
// blocks [0,256): A[j] = sum_i |s_j - s_i|  (col = b>>5, 32 chunks of 64 j)
// blocks [256,384): counting-rank windows   (col = (b-256)>>4, 16 chunks of 128 j)
__global__ __launch_bounds__(256) void k_prep(const float* __restrict__ logits,
                                              const float* __restrict__ dur,
                                              const int* __restrict__ ev,
                                              float* __restrict__ A,
                                              int* __restrict__ lohi,
                                              double* __restrict__ acc,
                                              unsigned* __restrict__ counter) {
    __shared__ float s[N];                   // 8 KB   (asum)
    __shared__ double part[256];             // 2 KB   (asum)
    __shared__ unsigned long long keys[N];   // 16 KB  (sortgt)
    __shared__ int pr[256], pv[256];         // 2 KB   (sortgt)

    int b = blockIdx.x;
    int tid = threadIdx.x;

    if (b == 0) {  // zero the accumulators + ticket for k_bce
        if (tid < 8) acc[tid] = 0.0;
        else if (tid == 8) counter[0] = 0u;
    }

    if (b < 256) {
        // ---- A-sum ----
        int col = b >> 5, chunk = b & 31;
        for (int k = 0; k < N / 256; ++k) {
            int i = tid + k * 256;
            s[i] = logits[i * NC + col];
        }
        __syncthreads();
        int jl = tid & 63, slice = tid >> 6;
        int j = chunk * 64 + jl;
        float sj = s[j];
        int base = slice * 512;
        double a0 = 0.0, a1 = 0.0, a2 = 0.0, a3 = 0.0;
        #pragma unroll 2
        for (int i = 0; i < 512; i += 4) {
            a0 += (double)fabsf(sj - s[base + i]);
            a1 += (double)fabsf(sj - s[base + i + 1]);
            a2 += (double)fabsf(sj - s[base + i + 2]);
            a3 += (double)fabsf(sj - s[base + i + 3]);
        }
        part[tid] = (a0 + a1) + (a2 + a3);
        __syncthreads();
        if (tid < 64) {
            double v = ((part[tid] + part[tid + 64]) + part[tid + 128]) + part[tid + 192];
            A[col * N + j] = (float)v;
        }
    } else {
        // ---- counting-rank GT windows ----
        // key = (dur_bits<<32)|(i<<1)|e : ascending u64 == stable ascending by d
        int b2 = b - 256;
        int col = b2 >> 4, chunk = b2 & 15;
        for (int k = 0; k < N / 256; ++k) {
            int i = tid + k * 256;
            unsigned int db = __float_as_uint(dur[i * NC + col]);  // dur in [0,1)
            int e = ev[i * NC + col];
            keys[i] = ((unsigned long long)db << 32) | (unsigned int)((i << 1) | e);
        }
        __syncthreads();
        int jl = tid & 127, half = tid >> 7;
        int j = chunk * 128 + jl;
        unsigned long long kj = keys[j];
        int base = half * 1024;
        int rank = 0, evlt = 0;
        #pragma unroll 4
        for (int i = 0; i < 1024; ++i) {
            unsigned long long ki = keys[base + i];
            int lt = (ki < kj) ? 1 : 0;
            rank += lt;
            evlt += lt & (int)(ki & 1ull);
        }
        pr[tid] = rank;
        pv[tid] = evlt;
        __syncthreads();
        if (half == 0) {
            int r = rank + pr[tid + 128];
            int v = evlt + pv[tid + 128];
            int e = (int)(kj & 1ull);
            int hi = e ? (r + 1) : N;
            lohi[col * N + j] = v | (hi << 16);
        }
    }
}

// ---------------- Kernel 2: softmax+BCE, wave/row, fused finalize -------------
// log p_j     = (t_j - m) - L
// log1p(-p_j) = log(S - e_j) - L
__global__ __launch_bounds__(256, 8) void k_bce(const float* __restrict__ logits,
                                                const float* __restrict__ A,
                                                const int* __restrict__ lohi,
                                                double* __restrict__ acc,
                                                unsigned* __restrict__ counter,
                                                float* __restrict__ out) {
    int col = blockIdx.x >> 8;   // 0..7
    int rg  = blockIdx.x & 255;  // 0..255 (8 rows each)
    __shared__ float2 sa[N];     // {s_j, A_j} -> ds_read_b64
    __shared__ double bsum[4];
    int tid = threadIdx.x;
    for (int k = 0; k < N / 256; ++k) {
        int i = tid + k * 256;
        sa[i] = make_float2(logits[i * NC + col], A[col * N + i]);
    }
    __syncthreads();

    int wave = tid >> 6, lane = tid & 63;
    double rsum = 0.0;

    for (int rep = 0; rep < 2; ++rep) {
        int row = rg * 8 + wave * 2 + rep;
        float scale = (float)(N - 1 - 2 * row);

        // pass 1: t_j = scale*s_j - A_j (cached in regs), row max
        float t[32];
        float m = -INFINITY;
        #pragma unroll
        for (int k = 0; k < 32; ++k) {
            float2 v = sa[lane + (k << 6)];
            t[k] = fmaf(scale, v.x, -v.y);
            m = fmaxf(m, t[k]);
        }
        #pragma unroll
        for (int off = 32; off > 0; off >>= 1)
            m = fmaxf(m, __shfl_xor(m, off, 64));

        // pass 2: S = sum exp(t-m), f32 partials (breaks dependency chains)
        float se0 = 0.0f, se1 = 0.0f;
        #pragma unroll
        for (int k = 0; k < 32; k += 2) {
            se0 += __expf(t[k] - m);
            se1 += __expf(t[k + 1] - m);
        }
        float se = se0 + se1;
        #pragma unroll
        for (int off = 32; off > 0; off >>= 1)
            se += __shfl_xor(se, off, 64);
        float S = se;
        float L = __logf(S);
        float mL = m + L;

        int lh = lohi[col * N + row];
        int lo = lh & 0xffff, hi = (lh >> 16) & 0xffff;
        unsigned wlen = (unsigned)(hi - lo);

        // pass 3: a1 = sum_j l1mp; a2 = sum_window (lp - l1mp)
        float a10 = 0.0f, a11 = 0.0f, a20 = 0.0f, a21 = 0.0f;
        #pragma unroll
        for (int k = 0; k < 32; k += 2) {
            {
                float e  = __expf(t[k] - m);
                float d  = fmaxf(S - e, 0.0f);
                float l1 = fmaxf(__logf(d) - L, -100.0f);
                a10 += l1;
                int j = lane + (k << 6);
                float w = ((unsigned)(j - lo) < wlen)
                            ? (fmaxf(t[k] - mL, -100.0f) - l1) : 0.0f;
                a20 += w;
            }
            {
                float e  = __expf(t[k + 1] - m);
                float d  = fmaxf(S - e, 0.0f);
                float l1 = fmaxf(__logf(d) - L, -100.0f);
                a11 += l1;
                int j = lane + ((k + 1) << 6);
                float w = ((unsigned)(j - lo) < wlen)
                            ? (fmaxf(t[k + 1] - mL, -100.0f) - l1) : 0.0f;
                a21 += w;
            }
        }
        float a1 = a10 + a11, a2 = a20 + a21;
        #pragma unroll
        for (int off = 32; off > 0; off >>= 1) {
            a1 += __shfl_xor(a1, off, 64);
            a2 += __shfl_xor(a2, off, 64);
        }
        float y = 1.0f / (float)(hi - lo);
        rsum += (double)a1 + (double)y * (double)a2;
    }

    // block-level combine -> 1 atomic per block, then ticket finalize
    if (lane == 0) bsum[wave] = rsum;
    __syncthreads();
    if (tid == 0) {
        double tot = (bsum[0] + bsum[1]) + (bsum[2] + bsum[3]);
        atomicAdd(&acc[col], tot);
        __threadfence();
        unsigned old = atomicAdd(counter, 1u);
        if (old == (unsigned)(NC * 256 - 1)) {  // last block: masked mean
            __threadfence();
            float ssum = 0.0f;
            int cnt = 0;
            for (int c = 0; c < NC; ++c) {
                double av = atomicAdd(&acc[c], 0.0);  // coherent read
                float lc = (float)(-av / ((double)N * (double)N));
                if (lc > 0.0f) { ssum += lc; cnt++; }
            }
            out[0] = ssum / (float)(cnt > 0 ? cnt : 1);
        }
    }
}

extern "C" void kernel_launch(void* const* d_in, const int* in_sizes, int n_in,
                              void* d_out, int out_size, void* d_ws, size_t ws_size,
                              hipStream_t stream) {
    const float* logits    = (const float*)d_in[0];
    const int*   events    = (const int*)d_in[1];
    const float* durations = (const float*)d_in[2];
    float* out = (float*)d_out;

    char* ws = (char*)d_ws;
    double*   acc     = (double*)ws;
    float*    A       = (float*)(ws + 64);
    int*      lohi    = (int*)(ws + 64 + (size_t)NC * N * sizeof(float));
    unsigned* counter = (unsigned*)(ws + 64 + 2 * (size_t)NC * N * sizeof(float));

    k_prep<<<dim3(384), 256, 0, stream>>>(logits, durations, events, A, lohi, acc, counter);
    k_bce<<<dim3(NC * 256), 256, 0, stream>>>(logits, A, lohi, acc, counter, out);
}

// Round 4
// 187.423 us; speedup vs baseline: 1.0897x; 1.0897x over previous
//
#include <hip/hip_runtime.h>
#include <hip/hip_bf16.h>
#include <math.h>

#define N 2048
#define NC 8

// ws layout:
//   [0, 64)             : double acc[8]        (zeroed by k_prep block 0)
//   [64, 64+64K)        : float  A[8][2048]
//   [64+64K, 64+128K)   : int    lohi[8][2048] (lo | hi<<16, per ORIGINAL row)
//   [64+128K, +4)       : unsigned counter     (ticket for fused finalize)

#if __has_builtin(__builtin_amdgcn_exp2f)
__device__ __forceinline__ float fexp2(float x) { return __builtin_amdgcn_exp2f(x); }
#else
__device__ __forceinline__ float fexp2(float x) { return exp2f(x); }
#endif
#if __has_builtin(__builtin_amdgcn_logf)
__device__ __forceinline__ float flog2(float x) { return __builtin_amdgcn_logf(x); }
#else
__device__ __forceinline__ float flog2(float x) { return log2f(x); }
#endif

#define INV_LN2 1.4426950408889634f
#define LN2_D   0.6931471805599453
#define CLAMP2  (-144.26950408889634f)   /* -100/ln2 : clamp in log2 domain */

// ---------------- Kernel 1: fused A-sum + counting-rank GT + acc zeroing ------
// blocks [0,256):   A[j] = sum_i |s_j - s_i|   (col = b>>5, 32 chunks of 64 j)
// blocks [256,512): counting-rank windows      (col = b2>>5, 32 chunks of 64 j)
__global__ __launch_bounds__(256) void k_prep(const float* __restrict__ logits,
                                              const float* __restrict__ dur,
                                              const int* __restrict__ ev,
                                              float* __restrict__ A,
                                              int* __restrict__ lohi,
                                              double* __restrict__ acc,
                                              unsigned* __restrict__ counter) {
    __shared__ float s[N];                   // 8 KB   (asum)
    __shared__ double part[256];             // 2 KB   (asum)
    __shared__ unsigned long long keys[N];   // 16 KB  (sortgt)
    __shared__ int pr[256], pv[256];         // 2 KB   (sortgt)

    int b = blockIdx.x;
    int tid = threadIdx.x;

    if (b == 0) {  // zero accumulators + ticket for k_bce (stream-ordered before k_bce)
        if (tid < 8) acc[tid] = 0.0;
        else if (tid == 8) counter[0] = 0u;
    }

    if (b < 256) {
        // ---- A-sum ----
        int col = b >> 5, chunk = b & 31;
        for (int k = 0; k < N / 256; ++k) {
            int i = tid + k * 256;
            s[i] = logits[i * NC + col];
        }
        __syncthreads();
        int jl = tid & 63, slice = tid >> 6;
        int j = chunk * 64 + jl;
        float sj = s[j];
        int base = slice * 512;
        double a0 = 0.0, a1 = 0.0, a2 = 0.0, a3 = 0.0;
        #pragma unroll 2
        for (int i = 0; i < 512; i += 4) {
            a0 += (double)fabsf(sj - s[base + i]);
            a1 += (double)fabsf(sj - s[base + i + 1]);
            a2 += (double)fabsf(sj - s[base + i + 2]);
            a3 += (double)fabsf(sj - s[base + i + 3]);
        }
        part[tid] = (a0 + a1) + (a2 + a3);
        __syncthreads();
        if (tid < 64) {
            double v = ((part[tid] + part[tid + 64]) + part[tid + 128]) + part[tid + 192];
            A[col * N + j] = (float)v;
        }
    } else {
        // ---- counting-rank GT windows ----
        // key = (dur_bits<<32)|(i<<1)|e : ascending u64 == stable ascending by d
        int b2 = b - 256;
        int col = b2 >> 5, chunk = b2 & 31;
        for (int k = 0; k < N / 256; ++k) {
            int i = tid + k * 256;
            unsigned int db = __float_as_uint(dur[i * NC + col]);  // dur in [0,1)
            int e = ev[i * NC + col];
            keys[i] = ((unsigned long long)db << 32) | (unsigned int)((i << 1) | e);
        }
        __syncthreads();
        int jl = tid & 63, slice = tid >> 6;
        int j = chunk * 64 + jl;
        unsigned long long kj = keys[j];
        int base = slice * 512;
        int rank = 0, evlt = 0;
        #pragma unroll 4
        for (int i = 0; i < 512; ++i) {
            unsigned long long ki = keys[base + i];
            int lt = (ki < kj) ? 1 : 0;
            rank += lt;
            evlt += lt & (int)(ki & 1ull);
        }
        pr[tid] = rank;
        pv[tid] = evlt;
        __syncthreads();
        if (tid < 64) {
            int r = ((pr[tid] + pr[tid + 64]) + pr[tid + 128]) + pr[tid + 192];
            int v = ((pv[tid] + pv[tid + 64]) + pv[tid + 128]) + pv[tid + 192];
            int e = (int)(kj & 1ull);
            int hi = e ? (r + 1) : N;
            lohi[col * N + j] = v | (hi << 16);
        }
    }
}

// ---------------- Kernel 2: softmax+BCE in log2 domain, fused finalize --------
// t2 = (scale*s - A)/ln2 ; e = 2^(t2-m2) ; S = sum e ; L2 = log2 S
// ln p      = ln2 * (t2 - m2 - L2)
// ln(1-p)   = ln2 * (log2(S - e) - L2)
__global__ __launch_bounds__(256, 6) void k_bce(const float* __restrict__ logits,
                                                const float* __restrict__ A,
                                                const int* __restrict__ lohi,
                                                double* __restrict__ acc,
                                                unsigned* __restrict__ counter,
                                                float* __restrict__ out) {
    int col = blockIdx.x >> 8;   // 0..7
    int rg  = blockIdx.x & 255;  // 0..255 (8 rows each)
    __shared__ float2 sa[N];     // {s/ln2, A/ln2} -> ds_read_b64
    __shared__ double bsum[4];
    int tid = threadIdx.x;
    for (int k = 0; k < N / 256; ++k) {
        int i = tid + k * 256;
        sa[i] = make_float2(logits[i * NC + col] * INV_LN2,
                            A[col * N + i] * INV_LN2);
    }
    __syncthreads();

    int wave = tid >> 6, lane = tid & 63;
    double rsum = 0.0;

    for (int rep = 0; rep < 2; ++rep) {
        int row = rg * 8 + wave * 2 + rep;
        float scale = (float)(N - 1 - 2 * row);

        // pass 1: t2 cached in regs, dual-chain row max
        float t[32];
        float m0 = -INFINITY, m1 = -INFINITY;
        #pragma unroll
        for (int k = 0; k < 32; k += 2) {
            float2 v0 = sa[lane + (k << 6)];
            float2 v1 = sa[lane + ((k + 1) << 6)];
            t[k]     = fmaf(scale, v0.x, -v0.y);
            t[k + 1] = fmaf(scale, v1.x, -v1.y);
            m0 = fmaxf(m0, t[k]);
            m1 = fmaxf(m1, t[k + 1]);
        }
        float m = fmaxf(m0, m1);
        #pragma unroll
        for (int off = 32; off > 0; off >>= 1)
            m = fmaxf(m, __shfl_xor(m, off, 64));

        // pass 2: S = sum 2^(t-m), dual f32 chains
        float se0 = 0.0f, se1 = 0.0f;
        #pragma unroll
        for (int k = 0; k < 32; k += 2) {
            se0 += fexp2(t[k] - m);
            se1 += fexp2(t[k + 1] - m);
        }
        float se = se0 + se1;
        #pragma unroll
        for (int off = 32; off > 0; off >>= 1)
            se += __shfl_xor(se, off, 64);
        float S  = se;
        float L2 = flog2(S);
        float mL = m + L2;            // t - mL = log2 p

        int lh = lohi[col * N + row];
        int lo = lh & 0xffff, hi = (lh >> 16) & 0xffff;
        unsigned wlen = (unsigned)(hi - lo);

        // pass 3: a1 = sum log2(1-p) ; a2 = sum_window (log2 p - log2(1-p))
        float a10 = 0.0f, a11 = 0.0f, a20 = 0.0f, a21 = 0.0f;
        #pragma unroll
        for (int k = 0; k < 32; k += 2) {
            {
                float e  = fexp2(t[k] - m);
                float d  = fmaxf(S - e, 0.0f);
                float l1 = fmaxf(flog2(d) - L2, CLAMP2);
                a10 += l1;
                int j = lane + (k << 6);
                float w = ((unsigned)(j - lo) < wlen)
                            ? (fmaxf(t[k] - mL, CLAMP2) - l1) : 0.0f;
                a20 += w;
            }
            {
                float e  = fexp2(t[k + 1] - m);
                float d  = fmaxf(S - e, 0.0f);
                float l1 = fmaxf(flog2(d) - L2, CLAMP2);
                a11 += l1;
                int j = lane + ((k + 1) << 6);
                float w = ((unsigned)(j - lo) < wlen)
                            ? (fmaxf(t[k + 1] - mL, CLAMP2) - l1) : 0.0f;
                a21 += w;
            }
        }
        float a1 = a10 + a11, a2 = a20 + a21;
        #pragma unroll
        for (int off = 32; off > 0; off >>= 1) {
            a1 += __shfl_xor(a1, off, 64);
            a2 += __shfl_xor(a2, off, 64);
        }
        float y = 1.0f / (float)(hi - lo);
        rsum += LN2_D * ((double)a1 + (double)y * (double)a2);
    }

    // block combine -> 1 atomic/block -> ticket finalize in last block
    if (lane == 0) bsum[wave] = rsum;
    __syncthreads();
    if (tid == 0) {
        double tot = (bsum[0] + bsum[1]) + (bsum[2] + bsum[3]);
        atomicAdd(&acc[col], tot);
        __threadfence();
        unsigned old = atomicAdd(counter, 1u);
        if (old == (unsigned)(NC * 256 - 1)) {  // last block: masked mean
            __threadfence();
            float ssum = 0.0f;
            int cnt = 0;
            for (int c = 0; c < NC; ++c) {
                double av = atomicAdd(&acc[c], 0.0);  // device-scope coherent read
                float lc = (float)(-av / ((double)N * (double)N));
                if (lc > 0.0f) { ssum += lc; cnt++; }
            }
            out[0] = ssum / (float)(cnt > 0 ? cnt : 1);
        }
    }
}

extern "C" void kernel_launch(void* const* d_in, const int* in_sizes, int n_in,
                              void* d_out, int out_size, void* d_ws, size_t ws_size,
                              hipStream_t stream) {
    const float* logits    = (const float*)d_in[0];
    const int*   events    = (const int*)d_in[1];
    const float* durations = (const float*)d_in[2];
    float* out = (float*)d_out;

    char* ws = (char*)d_ws;
    double*   acc     = (double*)ws;
    float*    A       = (float*)(ws + 64);
    int*      lohi    = (int*)(ws + 64 + (size_t)NC * N * sizeof(float));
    unsigned* counter = (unsigned*)(ws + 64 + 2 * (size_t)NC * N * sizeof(float));

    k_prep<<<dim3(512), 256, 0, stream>>>(logits, durations, events, A, lohi, acc, counter);
    k_bce<<<dim3(NC * 256), 256, 0, stream>>>(logits, A, lohi, acc, counter, out);
}

// Round 5
// 124.041 us; speedup vs baseline: 1.6465x; 1.5110x over previous
//
#include <hip/hip_runtime.h>
#include <hip/hip_bf16.h>
#include <math.h>

#define N 2048
#define NC 8

// ws layout:
//   [0, 64)             : double acc[8]        (zeroed by k_prep block 0)
//   [64, 64+64K)        : float  A[8][2048]
//   [64+64K, 64+128K)   : int    lohi[8][2048] (lo | hi<<16, per ORIGINAL row)
//   [64+128K, +4)       : unsigned counter     (ticket for fused finalize)

#if __has_builtin(__builtin_amdgcn_exp2f)
__device__ __forceinline__ float fexp2(float x) { return __builtin_amdgcn_exp2f(x); }
#else
__device__ __forceinline__ float fexp2(float x) { return exp2f(x); }
#endif
#if __has_builtin(__builtin_amdgcn_logf)
__device__ __forceinline__ float flog2(float x) { return __builtin_amdgcn_logf(x); }
#else
__device__ __forceinline__ float flog2(float x) { return log2f(x); }
#endif

#define INV_LN2 1.4426950408889634f
#define LN2_D   0.6931471805599453
#define CLAMP2  (-144.26950408889634f)   /* -100/ln2 : clamp in log2 domain */

// ---------------- Kernel 1: fused A-sum + counting-rank GT + acc zeroing ------
// blocks [0,256):   A[j] = sum_i |s_j - s_i|   (col = b>>5, 32 chunks of 64 j)
// blocks [256,512): counting-rank windows      (col = b2>>5, 32 chunks of 64 j)
__global__ __launch_bounds__(256) void k_prep(const float* __restrict__ logits,
                                              const float* __restrict__ dur,
                                              const int* __restrict__ ev,
                                              float* __restrict__ A,
                                              int* __restrict__ lohi,
                                              double* __restrict__ acc,
                                              unsigned* __restrict__ counter) {
    __shared__ float s[N];                   // 8 KB   (asum)
    __shared__ double part[256];             // 2 KB   (asum)
    __shared__ unsigned long long keys[N];   // 16 KB  (sortgt)
    __shared__ int pr[256], pv[256];         // 2 KB   (sortgt)

    int b = blockIdx.x;
    int tid = threadIdx.x;

    if (b == 0) {  // zero accumulators + ticket for k_bce (stream-ordered before k_bce)
        if (tid < 8) acc[tid] = 0.0;
        else if (tid == 8) counter[0] = 0u;
    }

    if (b < 256) {
        // ---- A-sum ----
        int col = b >> 5, chunk = b & 31;
        for (int k = 0; k < N / 256; ++k) {
            int i = tid + k * 256;
            s[i] = logits[i * NC + col];
        }
        __syncthreads();
        int jl = tid & 63, slice = tid >> 6;
        int j = chunk * 64 + jl;
        float sj = s[j];
        int base = slice * 512;
        double a0 = 0.0, a1 = 0.0, a2 = 0.0, a3 = 0.0;
        #pragma unroll 2
        for (int i = 0; i < 512; i += 4) {
            a0 += (double)fabsf(sj - s[base + i]);
            a1 += (double)fabsf(sj - s[base + i + 1]);
            a2 += (double)fabsf(sj - s[base + i + 2]);
            a3 += (double)fabsf(sj - s[base + i + 3]);
        }
        part[tid] = (a0 + a1) + (a2 + a3);
        __syncthreads();
        if (tid < 64) {
            double v = ((part[tid] + part[tid + 64]) + part[tid + 128]) + part[tid + 192];
            A[col * N + j] = (float)v;
        }
    } else {
        // ---- counting-rank GT windows ----
        // key = (dur_bits<<32)|(i<<1)|e : ascending u64 == stable ascending by d
        int b2 = b - 256;
        int col = b2 >> 5, chunk = b2 & 31;
        for (int k = 0; k < N / 256; ++k) {
            int i = tid + k * 256;
            unsigned int db = __float_as_uint(dur[i * NC + col]);  // dur in [0,1)
            int e = ev[i * NC + col];
            keys[i] = ((unsigned long long)db << 32) | (unsigned int)((i << 1) | e);
        }
        __syncthreads();
        int jl = tid & 63, slice = tid >> 6;
        int j = chunk * 64 + jl;
        unsigned long long kj = keys[j];
        int base = slice * 512;
        int rank = 0, evlt = 0;
        #pragma unroll 4
        for (int i = 0; i < 512; ++i) {
            unsigned long long ki = keys[base + i];
            int lt = (ki < kj) ? 1 : 0;
            rank += lt;
            evlt += lt & (int)(ki & 1ull);
        }
        pr[tid] = rank;
        pv[tid] = evlt;
        __syncthreads();
        if (tid < 64) {
            int r = ((pr[tid] + pr[tid + 64]) + pr[tid + 128]) + pr[tid + 192];
            int v = ((pv[tid] + pv[tid + 64]) + pv[tid + 128]) + pv[tid + 192];
            int e = (int)(kj & 1ull);
            int hi = e ? (r + 1) : N;
            lohi[col * N + j] = v | (hi << 16);
        }
    }
}

// ---------------- Kernel 2: softmax+BCE in log2 domain, fused finalize --------
// t2 = (scale*s - A)/ln2 ; e = 2^(t2-m2) ; S = sum e ; L2 = log2 S
// ln p      = ln2 * (t2 - m2 - L2)
// ln(1-p)   = ln2 * (log2(S - e) - L2)
// NOTE: plain __launch_bounds__(256). Min-waves clamps (r3: ,8 / r4: ,6) made
// the allocator spill t[32] wholesale to scratch (r4: 187 MB HBM traffic/dispatch,
// VALUBusy 16%). r2 proved this shape allocates cleanly at VGPR ~124 unclamped.
__global__ __launch_bounds__(256) void k_bce(const float* __restrict__ logits,
                                             const float* __restrict__ A,
                                             const int* __restrict__ lohi,
                                             double* __restrict__ acc,
                                             unsigned* __restrict__ counter,
                                             float* __restrict__ out) {
    int col = blockIdx.x >> 8;   // 0..7
    int rg  = blockIdx.x & 255;  // 0..255 (8 rows each)
    __shared__ float2 sa[N];     // {s/ln2, A/ln2} -> ds_read_b64
    __shared__ double bsum[4];
    int tid = threadIdx.x;
    for (int k = 0; k < N / 256; ++k) {
        int i = tid + k * 256;
        sa[i] = make_float2(logits[i * NC + col] * INV_LN2,
                            A[col * N + i] * INV_LN2);
    }
    __syncthreads();

    int wave = tid >> 6, lane = tid & 63;
    double rsum = 0.0;

    for (int rep = 0; rep < 2; ++rep) {
        int row = rg * 8 + wave * 2 + rep;
        float scale = (float)(N - 1 - 2 * row);

        // pass 1: t2 cached in regs, dual-chain row max
        float t[32];
        float m0 = -INFINITY, m1 = -INFINITY;
        #pragma unroll
        for (int k = 0; k < 32; k += 2) {
            float2 v0 = sa[lane + (k << 6)];
            float2 v1 = sa[lane + ((k + 1) << 6)];
            t[k]     = fmaf(scale, v0.x, -v0.y);
            t[k + 1] = fmaf(scale, v1.x, -v1.y);
            m0 = fmaxf(m0, t[k]);
            m1 = fmaxf(m1, t[k + 1]);
        }
        float m = fmaxf(m0, m1);
        #pragma unroll
        for (int off = 32; off > 0; off >>= 1)
            m = fmaxf(m, __shfl_xor(m, off, 64));

        // pass 2: S = sum 2^(t-m), dual f32 chains
        float se0 = 0.0f, se1 = 0.0f;
        #pragma unroll
        for (int k = 0; k < 32; k += 2) {
            se0 += fexp2(t[k] - m);
            se1 += fexp2(t[k + 1] - m);
        }
        float se = se0 + se1;
        #pragma unroll
        for (int off = 32; off > 0; off >>= 1)
            se += __shfl_xor(se, off, 64);
        float S  = se;
        float L2 = flog2(S);
        float mL = m + L2;            // t - mL = log2 p

        int lh = lohi[col * N + row];
        int lo = lh & 0xffff, hi = (lh >> 16) & 0xffff;
        unsigned wlen = (unsigned)(hi - lo);

        // pass 3: a1 = sum log2(1-p) ; a2 = sum_window (log2 p - log2(1-p))
        float a10 = 0.0f, a11 = 0.0f, a20 = 0.0f, a21 = 0.0f;
        #pragma unroll
        for (int k = 0; k < 32; k += 2) {
            {
                float e  = fexp2(t[k] - m);
                float d  = fmaxf(S - e, 0.0f);
                float l1 = fmaxf(flog2(d) - L2, CLAMP2);
                a10 += l1;
                int j = lane + (k << 6);
                float w = ((unsigned)(j - lo) < wlen)
                            ? (fmaxf(t[k] - mL, CLAMP2) - l1) : 0.0f;
                a20 += w;
            }
            {
                float e  = fexp2(t[k + 1] - m);
                float d  = fmaxf(S - e, 0.0f);
                float l1 = fmaxf(flog2(d) - L2, CLAMP2);
                a11 += l1;
                int j = lane + ((k + 1) << 6);
                float w = ((unsigned)(j - lo) < wlen)
                            ? (fmaxf(t[k + 1] - mL, CLAMP2) - l1) : 0.0f;
                a21 += w;
            }
        }
        float a1 = a10 + a11, a2 = a20 + a21;
        #pragma unroll
        for (int off = 32; off > 0; off >>= 1) {
            a1 += __shfl_xor(a1, off, 64);
            a2 += __shfl_xor(a2, off, 64);
        }
        float y = 1.0f / (float)(hi - lo);
        rsum += LN2_D * ((double)a1 + (double)y * (double)a2);
    }

    // block combine -> 1 atomic/block -> ticket finalize in last block
    if (lane == 0) bsum[wave] = rsum;
    __syncthreads();
    if (tid == 0) {
        double tot = (bsum[0] + bsum[1]) + (bsum[2] + bsum[3]);
        atomicAdd(&acc[col], tot);
        __threadfence();
        unsigned old = atomicAdd(counter, 1u);
        if (old == (unsigned)(NC * 256 - 1)) {  // last block: masked mean
            __threadfence();
            float ssum = 0.0f;
            int cnt = 0;
            for (int c = 0; c < NC; ++c) {
                double av = atomicAdd(&acc[c], 0.0);  // device-scope coherent read
                float lc = (float)(-av / ((double)N * (double)N));
                if (lc > 0.0f) { ssum += lc; cnt++; }
            }
            out[0] = ssum / (float)(cnt > 0 ? cnt : 1);
        }
    }
}

extern "C" void kernel_launch(void* const* d_in, const int* in_sizes, int n_in,
                              void* d_out, int out_size, void* d_ws, size_t ws_size,
                              hipStream_t stream) {
    const float* logits    = (const float*)d_in[0];
    const int*   events    = (const int*)d_in[1];
    const float* durations = (const float*)d_in[2];
    float* out = (float*)d_out;

    char* ws = (char*)d_ws;
    double*   acc     = (double*)ws;
    float*    A       = (float*)(ws + 64);
    int*      lohi    = (int*)(ws + 64 + (size_t)NC * N * sizeof(float));
    unsigned* counter = (unsigned*)(ws + 64 + 2 * (size_t)NC * N * sizeof(float));

    k_prep<<<dim3(512), 256, 0, stream>>>(logits, durations, events, A, lohi, acc, counter);
    k_bce<<<dim3(NC * 256), 256, 0, stream>>>(logits, A, lohi, acc, counter, out);
}